// Round 2
// baseline (312.090 us; speedup 1.0000x reference)
//
#include <hip/hip_runtime.h>

typedef unsigned short u16;
typedef __attribute__((ext_vector_type(4))) float f32x4;
typedef __attribute__((ext_vector_type(8))) short short8;

#define WIN_SZ 100
#define NWIN 41
#define NBATCH 8
#define SEQ 4096
#define DM 512
#define NHEAD 8
#define KD 64
#define NWINS (NBATCH * NWIN)    // 328
#define MROWS (NWINS * WIN_SZ)   // 32800
#define MBLKS 257                // ceil(32800/128)
#define TOKPB (NWIN * WIN_SZ)    // 4100
#define NQKV 1536

__device__ __forceinline__ u16 f2bf(float f) {
  union { float f; unsigned i; } v; v.f = f;
  unsigned r = (v.i + 0x7fffu + ((v.i >> 16) & 1u)) >> 16;
  return (u16)r;
}

// async global->LDS, 16B per lane; lds base wave-uniform (HW adds lane*16)
__device__ __forceinline__ void gl2lds16(const void* g, void* lds) {
  __builtin_amdgcn_global_load_lds(
      (const __attribute__((address_space(1))) void*)g,
      (__attribute__((address_space(3))) void*)lds, 16, 0, 0);
}

// ---------------- weights fp32 -> bf16 transposed + bias concat ----------------
__global__ void prep_k(const float* __restrict__ Wq, const float* __restrict__ Wk,
                       const float* __restrict__ Wv, const float* __restrict__ Wo,
                       const float* __restrict__ bq, const float* __restrict__ bk,
                       const float* __restrict__ bv,
                       u16* __restrict__ WqkvT, u16* __restrict__ WoT,
                       float* __restrict__ biasF, u16* __restrict__ zblk) {
  int idx = blockIdx.x * 256 + threadIdx.x;
  if (idx < NQKV * DM) {
    int n = idx >> 9, k = idx & 511;
    const float* W = (n < DM) ? Wq : ((n < 2 * DM) ? Wk : Wv);
    WqkvT[idx] = f2bf(W[k * DM + (n & 511)]);
  }
  if (idx < DM * DM) WoT[idx] = f2bf(Wo[(idx & 511) * DM + (idx >> 9)]);
  if (idx < DM) biasF[idx] = bq[idx];
  else if (idx < 2 * DM) biasF[idx] = bk[idx - DM];
  else if (idx < 3 * DM) biasF[idx] = bv[idx - 2 * DM];
  if (idx < 32) zblk[idx] = 0;
}

// ---------------- x fp32 -> bf16 with window-padding gather ----------------
// xbf row m: window token; rows where original index >= SEQ are zero.
__global__ void convx_k(const float* __restrict__ x, u16* __restrict__ xbf) {
  int i = blockIdx.x * 256 + threadIdx.x;     // float4-group index
  if (i >= MROWS * 128) return;
  int m = i >> 7;
  int c4 = (i & 127) * 4;
  int b = m / TOKPB, tk = m - b * TOKPB;
  float4 v = make_float4(0.f, 0.f, 0.f, 0.f);
  if (tk < SEQ) v = *(const float4*)(x + (size_t)(b * SEQ + tk) * DM + c4);
  u16 o[4] = {f2bf(v.x), f2bf(v.y), f2bf(v.z), f2bf(v.w)};
  *(uint2*)(xbf + (size_t)m * DM + c4) = *(const uint2*)o;
}

// ---------------- GEMM: C[M,N] = A[M,512] @ Bt[N,512]^T + bias ----------------
// OUTF32=0: bf16 out; OUTF32=1: fp32 out. A rows >= MROWS read zero block.
template <int OUTF32>
__global__ __launch_bounds__(256, 2)
void gemm_k(const u16* __restrict__ A, const u16* __restrict__ Bt,
            const float* __restrict__ bias, const u16* __restrict__ zsrc,
            void* __restrict__ Cout, int Ntot) {
  __shared__ u16 Alds[128 * 64];
  __shared__ u16 Blds[128 * 64];

  const int t = threadIdx.x;
  const int w = t >> 6;
  const int l = t & 63;
  const int nb = blockIdx.x, mb = blockIdx.y;
  const int m0 = mb * 128, n0 = nb * 128;
  const int lrow = t >> 3;
  const int lcol = (t & 7) * 8;

  const u16* abase[4];
  const u16* bbase[4];
#pragma unroll
  for (int i = 0; i < 4; ++i) {
    int m = m0 + i * 32 + lrow;
    abase[i] = (m < MROWS) ? (A + (size_t)m * DM) : nullptr;
    bbase[i] = Bt + (size_t)(n0 + i * 32 + lrow) * DM;
  }

  f32x4 acc[4][4] = {};
  const int wm = (w & 1) * 64;
  const int wn = (w >> 1) * 64;
  const int q = l >> 4, cl = l & 15;

  for (int k0 = 0; k0 < DM; k0 += 64) {
    __syncthreads();
#pragma unroll
    for (int i = 0; i < 4; ++i) {
      const u16* ga = abase[i] ? (abase[i] + k0 + lcol) : zsrc;
      gl2lds16(ga, &Alds[(i * 32 + w * 8) * 64]);
      gl2lds16(bbase[i] + k0 + lcol, &Blds[(i * 32 + w * 8) * 64]);
    }
    __syncthreads();
#pragma unroll
    for (int ks = 0; ks < 2; ++ks) {
      short8 av[4], bv_[4];
      const int ko = ks * 32 + q * 8;
#pragma unroll
      for (int mi = 0; mi < 4; ++mi)
        av[mi] = *(const short8*)&Alds[(wm + mi * 16 + cl) * 64 + ko];
#pragma unroll
      for (int ni = 0; ni < 4; ++ni)
        bv_[ni] = *(const short8*)&Blds[(wn + ni * 16 + cl) * 64 + ko];
#pragma unroll
      for (int mi = 0; mi < 4; ++mi)
#pragma unroll
        for (int ni = 0; ni < 4; ++ni)
          acc[mi][ni] = __builtin_amdgcn_mfma_f32_16x16x32_bf16(
              av[mi], bv_[ni], acc[mi][ni], 0, 0, 0);
    }
  }

#pragma unroll
  for (int mi = 0; mi < 4; ++mi) {
#pragma unroll
    for (int ni = 0; ni < 4; ++ni) {
      int col = n0 + wn + ni * 16 + cl;
      float bb = bias[col];
#pragma unroll
      for (int r = 0; r < 4; ++r) {
        int row = m0 + wm + mi * 16 + q * 4 + r;
        if (row < MROWS) {
          if (OUTF32)
            ((float*)Cout)[(size_t)row * Ntot + col] = acc[mi][ni][r] + bb;
          else
            ((u16*)Cout)[(size_t)row * Ntot + col] = f2bf(acc[mi][ni][r] + bb);
        }
      }
    }
  }
}

// ---------------- per-(window, head) attention ----------------
#define QKS 72   // Q/K LDS row stride (16B aligned)
#define PS 136   // P / Vt LDS row stride

__global__ __launch_bounds__(256, 2)
void attn_k(const u16* __restrict__ qkv, u16* __restrict__ obuf) {
  union SM {
    struct { u16 Q[112 * QKS]; u16 K[112 * QKS]; } qk;  // 32256 B
    u16 P[112 * PS];                                    // 30464 B
  };
  __shared__ SM sm;
  __shared__ u16 Vt[64 * PS];                           // 17408 B

  const int win = blockIdx.x, h = blockIdx.y;
  const int t = threadIdx.x, w = t >> 6, l = t & 63;
  const int q = l >> 4, cl = l & 15;
  const size_t base = (size_t)win * WIN_SZ * NQKV;
  const int qoff = h * KD, koff = DM + h * KD, voff = 2 * DM + h * KD;

  {
    const int lr = t >> 3, lc = (t & 7) * 8;
#pragma unroll
    for (int i = 0; i < 4; ++i) {
      int r = i * 32 + lr;
      if (r < WIN_SZ) {
        const u16* rp = qkv + base + (size_t)r * NQKV;
        uint4 vq = *(const uint4*)(rp + qoff + lc);
        *(uint4*)&sm.qk.Q[r * QKS + lc] = vq;
        uint4 vk = *(const uint4*)(rp + koff + lc);
        *(uint4*)&sm.qk.K[r * QKS + lc] = vk;
        uint4 vv = *(const uint4*)(rp + voff + lc);
        const u16* pv = (const u16*)&vv;
#pragma unroll
        for (int j = 0; j < 8; ++j) Vt[(lc + j) * PS + r] = pv[j];
      }
    }
    for (int idx = t; idx < 12 * QKS; idx += 256) {  // zero Q/K rows 100..111
      int r = WIN_SZ + idx / QKS, c = idx % QKS;
      sm.qk.Q[r * QKS + c] = 0;
      sm.qk.K[r * QKS + c] = 0;
    }
    for (int idx = t; idx < 64 * 36; idx += 256) {   // zero Vt cols 100..135
      int r = idx / 36, c = WIN_SZ + idx % 36;
      Vt[r * PS + c] = 0;
    }
  }
  __syncthreads();

  // wave w owns m-tiles {w, w+4} (wave 3: just {3}); 7 m-tiles cover 112 rows
  const int nmt = (w < 3) ? 2 : 1;
  const int mt0 = w, mt1 = w + 4;

  f32x4 accs[2][7];
#pragma unroll
  for (int im = 0; im < 2; ++im) {
    if (im < nmt) {
      const int mt = (im == 0) ? mt0 : mt1;
      const int ar = (mt * 16 + cl) * QKS + q * 8;
      short8 a0 = *(const short8*)&sm.qk.Q[ar];
      short8 a1 = *(const short8*)&sm.qk.Q[ar + 32];
#pragma unroll
      for (int nt = 0; nt < 7; ++nt) {
        const int br = (nt * 16 + cl) * QKS + q * 8;
        short8 b0 = *(const short8*)&sm.qk.K[br];
        short8 b1 = *(const short8*)&sm.qk.K[br + 32];
        f32x4 c = {};
        c = __builtin_amdgcn_mfma_f32_16x16x32_bf16(a0, b0, c, 0, 0, 0);
        c = __builtin_amdgcn_mfma_f32_16x16x32_bf16(a1, b1, c, 0, 0, 0);
        accs[im][nt] = c;
      }
    }
  }

  // softmax over full row (cols 0..99 valid; 100..111 masked), in registers.
  // row = (q, r) within 16-lane group; reduce across cl with shfl_xor.
  const float scale = 0.125f;  // 1/sqrt(64)
#pragma unroll
  for (int im = 0; im < 2; ++im) {
    if (im < nmt) {
#pragma unroll
      for (int r = 0; r < 4; ++r) {
        float mx = -1e30f;
#pragma unroll
        for (int nt = 0; nt < 7; ++nt) {
          float s = accs[im][nt][r] * scale;
          if ((nt < 6) || (cl < 4)) mx = fmaxf(mx, s);
        }
        mx = fmaxf(mx, __shfl_xor(mx, 1, 64));
        mx = fmaxf(mx, __shfl_xor(mx, 2, 64));
        mx = fmaxf(mx, __shfl_xor(mx, 4, 64));
        mx = fmaxf(mx, __shfl_xor(mx, 8, 64));
        float sum = 0.f;
#pragma unroll
        for (int nt = 0; nt < 7; ++nt) {
          float s = accs[im][nt][r] * scale;
          bool valid = (nt < 6) || (cl < 4);
          float e = valid ? __expf(s - mx) : 0.f;
          accs[im][nt][r] = e;
          sum += e;
        }
        sum += __shfl_xor(sum, 1, 64);
        sum += __shfl_xor(sum, 2, 64);
        sum += __shfl_xor(sum, 4, 64);
        sum += __shfl_xor(sum, 8, 64);
        float inv = 1.0f / sum;
#pragma unroll
        for (int nt = 0; nt < 7; ++nt) accs[im][nt][r] *= inv;
      }
    }
  }
  __syncthreads();  // all Q/K reads done before P overwrites the union

#pragma unroll
  for (int im = 0; im < 2; ++im) {
    if (im < nmt) {
      const int mt = (im == 0) ? mt0 : mt1;
#pragma unroll
      for (int nt = 0; nt < 7; ++nt)
#pragma unroll
        for (int r = 0; r < 4; ++r)
          sm.P[(mt * 16 + q * 4 + r) * PS + nt * 16 + cl] = f2bf(accs[im][nt][r]);
    }
  }
  for (int idx = t; idx < 112 * 24; idx += 256) {  // zero P cols 112..135
    int r = idx / 24, c = 112 + idx % 24;
    sm.P[r * PS + c] = 0;
  }
  __syncthreads();

  // O = P @ V  (A-frag from P rows, B-frag from Vt rows = d index)
  f32x4 acco[2][4] = {};
#pragma unroll
  for (int ks = 0; ks < 4; ++ks) {
    const int ko = ks * 32 + q * 8;
    short8 a0 = *(const short8*)&sm.P[(mt0 * 16 + cl) * PS + ko];
    short8 a1 = a0;
    if (nmt == 2) a1 = *(const short8*)&sm.P[(mt1 * 16 + cl) * PS + ko];
#pragma unroll
    for (int nt = 0; nt < 4; ++nt) {
      short8 b = *(const short8*)&Vt[(nt * 16 + cl) * PS + ko];
      acco[0][nt] = __builtin_amdgcn_mfma_f32_16x16x32_bf16(a0, b, acco[0][nt], 0, 0, 0);
      if (nmt == 2)
        acco[1][nt] = __builtin_amdgcn_mfma_f32_16x16x32_bf16(a1, b, acco[1][nt], 0, 0, 0);
    }
  }

  const size_t orow0 = (size_t)win * WIN_SZ;
#pragma unroll
  for (int im = 0; im < 2; ++im) {
    if (im < nmt) {
      const int mt = (im == 0) ? mt0 : mt1;
#pragma unroll
      for (int nt = 0; nt < 4; ++nt)
#pragma unroll
        for (int r = 0; r < 4; ++r) {
          int row = mt * 16 + q * 4 + r;
          if (row < WIN_SZ)
            obuf[(orow0 + row) * DM + h * KD + nt * 16 + cl] = f2bf(acco[im][nt][r]);
        }
    }
  }
}

extern "C" void kernel_launch(void* const* d_in, const int* in_sizes, int n_in,
                              void* d_out, int out_size, void* d_ws, size_t ws_size,
                              hipStream_t stream) {
  const float* x  = (const float*)d_in[0];
  const float* Wq = (const float*)d_in[1];
  const float* bq = (const float*)d_in[2];
  const float* Wk = (const float*)d_in[3];
  const float* bk = (const float*)d_in[4];
  const float* Wv = (const float*)d_in[5];
  const float* bv = (const float*)d_in[6];
  const float* Wo = (const float*)d_in[7];
  const float* bo = (const float*)d_in[8];

  u16* ws    = (u16*)d_ws;
  u16* xbf   = ws;                            // [32800][512]  bf16  33.6 MB
  u16* qkv   = xbf + (size_t)MROWS * DM;      // [32800][1536] bf16 100.8 MB
  u16* obuf  = qkv + (size_t)MROWS * NQKV;    // [32800][512]  bf16  33.6 MB
  u16* WqkvT = obuf + (size_t)MROWS * DM;     // [1536][512]   bf16
  u16* WoT   = WqkvT + (size_t)NQKV * DM;     // [512][512]    bf16
  u16* zblk  = WoT + (size_t)DM * DM;         // 64 B zeros
  float* biasF = (float*)(zblk + 128);        // [1536] fp32

  prep_k<<<dim3((NQKV * DM + 255) / 256), dim3(256), 0, stream>>>(
      Wq, Wk, Wv, Wo, bq, bk, bv, WqkvT, WoT, biasF, zblk);
  convx_k<<<dim3((MROWS * 128 + 255) / 256), dim3(256), 0, stream>>>(x, xbf);
  gemm_k<0><<<dim3(NQKV / 128, MBLKS), dim3(256), 0, stream>>>(
      xbf, WqkvT, biasF, zblk, qkv, NQKV);
  attn_k<<<dim3(NWINS, NHEAD), dim3(256), 0, stream>>>(qkv, obuf);
  gemm_k<1><<<dim3(DM / 128, MBLKS), dim3(256), 0, stream>>>(
      obuf, WoT, bo, zblk, d_out, DM);
}